// Round 1
// baseline (26.822 us; speedup 1.0000x reference)
//
#include <hip/hip_runtime.h>
#include <math.h>

// Problem constants: B=2, N=1024, H=128, E=32
#define NN 1024
#define HH 128
#define EE 32

// Fused-weight derivation:
//   t[bn,o]  = sum_h nf[bn,h]*Wt[o,h] + bt[o]
//   hi[bn,e] = sum_o t[bn,o]*W1[e,o]          (W1i = W1[:, :128])
//            = sum_h nf[bn,h]*Ai[e,h] + ci[e],  Ai[e,h]=sum_o W1[e,o]*Wt[o,h]
//   hj[bn,e] likewise with W1j = W1[:,128:].
// We store At transposed: At[k*64 + e'] with e'=0..31 -> i-half, 32..63 -> j-half.
// c[e'] = sum_o W1row[o]*bt[o]  (+ b1[e] folded into the i-half).
// Then  ew(n,m) = b2 + sum_e relu(g[n,e] + g[m,32+e]) * W2[e]
//       out    = sigmoid(ew) * adj[n,m]   (exactly 0 where adj==0 -> skip)

// ws layout (floats): At[128*64] | c[64] | gall[2048*64]

__global__ __launch_bounds__(128) void prep_kernel(
    const float* __restrict__ Wt, const float* __restrict__ bt,
    const float* __restrict__ W1, const float* __restrict__ b1,
    float* __restrict__ At, float* __restrict__ c)
{
    const int ep   = blockIdx.x;   // 0..63 (fused e' index)
    const int e    = ep & 31;
    const int half = ep >> 5;      // 0 -> W1i, 1 -> W1j
    const int tid  = threadIdx.x;  // 0..127

    __shared__ float s_w1[128];
    __shared__ float s_bt[128];
    __shared__ float s_red[128];

    s_w1[tid] = W1[e * 256 + half * 128 + tid];
    s_bt[tid] = bt[tid];
    __syncthreads();

    // At[k, e'] = sum_o w1row[o] * Wt[o, k]   (k = tid; Wt reads coalesced)
    float acc = 0.f;
    #pragma unroll 4
    for (int o = 0; o < 128; ++o)
        acc = fmaf(s_w1[o], Wt[o * 128 + tid], acc);
    At[tid * 64 + ep] = acc;

    // c[e'] = sum_o w1row[o]*bt[o]  (+ b1 folded into i-half)
    s_red[tid] = s_w1[tid] * s_bt[tid];
    __syncthreads();
    for (int s = 64; s > 0; s >>= 1) {
        if (tid < s) s_red[tid] += s_red[tid + s];
        __syncthreads();
    }
    if (tid == 0) c[ep] = s_red[0] + (half == 0 ? b1[e] : 0.f);
}

// g[bn, e'] = c[e'] + sum_k nf[bn,k] * At[k,e']
// One wave per node: lane = krep*16 + g; lane owns k = 4i+krep, e' = 4g..4g+3.
// At float4 reads are fully coalesced (1024 contiguous bytes per wave-instr).
__global__ __launch_bounds__(256) void gfeat_kernel(
    const float* __restrict__ nf, const float* __restrict__ At,
    const float* __restrict__ c, float* __restrict__ gall)
{
    const int tid  = threadIdx.x;
    const int bn   = blockIdx.x * 4 + (tid >> 6);  // wave-uniform
    const int lane = tid & 63;
    const int g    = lane & 15;
    const int krep = lane >> 4;

    const float* nfrow = nf + bn * 128;
    float4 acc = make_float4(0.f, 0.f, 0.f, 0.f);

    #pragma unroll 8
    for (int i = 0; i < 32; ++i) {
        const int k = 4 * i + krep;
        const float nv = nfrow[k];
        const float4 av = *reinterpret_cast<const float4*>(At + k * 64 + 4 * g);
        acc.x = fmaf(nv, av.x, acc.x);
        acc.y = fmaf(nv, av.y, acc.y);
        acc.z = fmaf(nv, av.z, acc.z);
        acc.w = fmaf(nv, av.w, acc.w);
    }

    // reduce over krep groups: lanes {l, l^16, l^32, l^48} share (g)
    acc.x += __shfl_xor(acc.x, 16, 64);
    acc.y += __shfl_xor(acc.y, 16, 64);
    acc.z += __shfl_xor(acc.z, 16, 64);
    acc.w += __shfl_xor(acc.w, 16, 64);
    acc.x += __shfl_xor(acc.x, 32, 64);
    acc.y += __shfl_xor(acc.y, 32, 64);
    acc.z += __shfl_xor(acc.z, 32, 64);
    acc.w += __shfl_xor(acc.w, 32, 64);

    if (krep == 0) {
        const float4 cv = *reinterpret_cast<const float4*>(c + 4 * g);
        float4 r;
        r.x = acc.x + cv.x;
        r.y = acc.y + cv.y;
        r.z = acc.z + cv.z;
        r.w = acc.w + cv.w;
        *reinterpret_cast<float4*>(gall + bn * 64 + 4 * g) = r;
    }
}

// One block per (b, n) output row; thread handles 4 m's via float4.
__global__ __launch_bounds__(256) void edge_kernel(
    const float* __restrict__ adj, const float* __restrict__ gall,
    const float* __restrict__ W2, const float* __restrict__ b2,
    float* __restrict__ out)
{
    const int n   = blockIdx.x;
    const int b   = blockIdx.y;
    const int tid = threadIdx.x;

    __shared__ float s_u[32];   // g[n, 0:32]  (= hi + b1 + ci)
    __shared__ float s_w2[32];
    if (tid < 32) {
        s_u[tid]  = gall[(b * NN + n) * 64 + tid];
        s_w2[tid] = W2[tid];
    }
    __syncthreads();
    const float b2v = b2[0];

    const int m0 = tid * 4;
    const float4 a4 = *reinterpret_cast<const float4*>(adj + n * NN + m0);
    float4 r4;
    const float* ap = &a4.x;
    float* rp = &r4.x;

    #pragma unroll
    for (int cc = 0; cc < 4; ++cc) {
        const float a = ap[cc];
        float r = 0.f;
        if (a != 0.f) {
            const float* gj = gall + (b * NN + m0 + cc) * 64 + 32;
            float ew = b2v;
            #pragma unroll
            for (int j = 0; j < 8; ++j) {
                const float4 gv = *reinterpret_cast<const float4*>(gj + 4 * j);
                const float v0 = fmaxf(s_u[4 * j + 0] + gv.x, 0.f);
                const float v1 = fmaxf(s_u[4 * j + 1] + gv.y, 0.f);
                const float v2 = fmaxf(s_u[4 * j + 2] + gv.z, 0.f);
                const float v3 = fmaxf(s_u[4 * j + 3] + gv.w, 0.f);
                ew = fmaf(v0, s_w2[4 * j + 0], ew);
                ew = fmaf(v1, s_w2[4 * j + 1], ew);
                ew = fmaf(v2, s_w2[4 * j + 2], ew);
                ew = fmaf(v3, s_w2[4 * j + 3], ew);
            }
            r = a / (1.f + __expf(-ew));
        }
        rp[cc] = r;
    }
    *reinterpret_cast<float4*>(out + (size_t)(b * NN + n) * NN + m0) = r4;
}

extern "C" void kernel_launch(void* const* d_in, const int* in_sizes, int n_in,
                              void* d_out, int out_size, void* d_ws, size_t ws_size,
                              hipStream_t stream)
{
    const float* nf  = (const float*)d_in[0];
    const float* adj = (const float*)d_in[1];
    const float* Wt  = (const float*)d_in[2];
    const float* bt  = (const float*)d_in[3];
    const float* W1  = (const float*)d_in[4];
    const float* b1  = (const float*)d_in[5];
    const float* W2  = (const float*)d_in[6];
    const float* b2  = (const float*)d_in[7];
    float* out = (float*)d_out;

    float* At   = (float*)d_ws;       // 128*64 floats
    float* c    = At + 128 * 64;      // 64 floats
    float* gall = c + 64;             // 2048*64 floats (16B-aligned: 33024 B offset)

    hipLaunchKernelGGL(prep_kernel, dim3(64), dim3(128), 0, stream,
                       Wt, bt, W1, b1, At, c);
    hipLaunchKernelGGL(gfeat_kernel, dim3(512), dim3(256), 0, stream,
                       nf, At, c, gall);
    hipLaunchKernelGGL(edge_kernel, dim3(NN, 2), dim3(256), 0, stream,
                       adj, gall, W2, b2, out);
}